// Round 11
// baseline (552.439 us; speedup 1.0000x reference)
//
#include <hip/hip_runtime.h>
#include <hip/hip_bf16.h>
#include <stdint.h>

// Problem constants
#define B_    2
#define SQ    2048
#define H_    4096
#define NHEAD 32
#define HDIM  128
#define NGRP  2
#define QKVN  4608          // NH*HD + 2*NG*HD
#define SCALE 0.08838834764831845f   // 1/sqrt(128), coeff=1
#define QSCALE (0.08838834764831845f * 1.4426950408889634f)  // SCALE*log2(e), exp2 softmax

typedef __attribute__((ext_vector_type(8))) short bf16x8;
typedef __attribute__((ext_vector_type(4))) short bf16x4;
typedef __attribute__((ext_vector_type(4))) float f32x4;

__device__ __forceinline__ float b2f(short s) {
  union { float f; unsigned u; } x; x.u = ((unsigned)(unsigned short)s) << 16; return x.f;
}
__device__ __forceinline__ short f2b(float f) {
  union { float f; unsigned u; } x; x.f = f;
  unsigned r = x.u + 0x7fffu + ((x.u >> 16) & 1u);  // RNE
  return (short)(r >> 16);
}
__device__ __forceinline__ void gll16(const void* g, void* l) {
  __builtin_amdgcn_global_load_lds(
      (const __attribute__((address_space(1))) unsigned int*)g,
      (__attribute__((address_space(3))) unsigned int*)l, 16, 0, 0);
}

// ---------------- f32 -> bf16 convert (vectorized) ----------------
__global__ void conv_f32_bf16(const float* __restrict__ x, short* __restrict__ y, int n) {
  int i = (blockIdx.x * blockDim.x + threadIdx.x) * 4;
  if (i >= n) return;
  float4 v = *(const float4*)(x + i);
  union { short s[4]; uint2 u; } o;
  o.s[0] = f2b(v.x); o.s[1] = f2b(v.y); o.s[2] = f2b(v.z); o.s[3] = f2b(v.w);
  *(uint2*)(y + i) = o.u;
}

// ---------------- transpose f32 (RxC) -> bf16 (CxR), 64x64 tile, float4 loads ------
__global__ void transpose_f32_bf16(const float* __restrict__ W, short* __restrict__ Wt,
                                   int R, int C) {
  __shared__ float tile[64][65];
  int c0 = blockIdx.x * 64, r0 = blockIdx.y * 64;
  int tx = threadIdx.x & 15, ty = threadIdx.x >> 4;
  #pragma unroll
  for (int i = 0; i < 4; ++i) {
    float4 v = *(const float4*)(W + (size_t)(r0 + ty + 16 * i) * C + c0 + tx * 4);
    tile[ty + 16 * i][tx * 4 + 0] = v.x;
    tile[ty + 16 * i][tx * 4 + 1] = v.y;
    tile[ty + 16 * i][tx * 4 + 2] = v.z;
    tile[ty + 16 * i][tx * 4 + 3] = v.w;
  }
  __syncthreads();
  #pragma unroll
  for (int i = 0; i < 4; ++i) {
    int orow = ty + 16 * i;
    bf16x4 o;
    #pragma unroll
    for (int j = 0; j < 4; ++j) o[j] = f2b(tile[tx * 4 + j][orow]);
    *(bf16x4*)(Wt + (size_t)(c0 + orow) * R + r0 + tx * 4) = o;
  }
}

// ---------------- 128x128 bf16 MFMA GEMM (proven m97 structure, 2D grid) ----------------
template<bool BIAS, bool OUTF32>
__global__ __launch_bounds__(256, 2) void gemm_bf16(
    const short* __restrict__ A, const short* __restrict__ Bt,
    const float* __restrict__ bias, short* __restrict__ outb,
    float* __restrict__ outf, int M, int N, int K)
{
  __shared__ short smA[128 * 64];
  __shared__ short smB[128 * 64];
  const int t = threadIdx.x;
  const int l = t & 63;
  const int w = t >> 6;
  const int wr = w >> 1, wc = w & 1;
  const int m0 = blockIdx.y * 128, n0 = blockIdx.x * 128;

  const f32x4 z = {0.f, 0.f, 0.f, 0.f};
  f32x4 acc[4][4];
  #pragma unroll
  for (int m = 0; m < 4; ++m)
    #pragma unroll
    for (int n = 0; n < 4; ++n) acc[m][n] = z;

  for (int k0 = 0; k0 < K; k0 += 64) {
    __syncthreads();
    #pragma unroll
    for (int i = 0; i < 4; ++i) {
      int c = t + i * 256;
      int row = c >> 3, slot = c & 7;
      int ss = slot ^ (row & 7);
      gll16(A  + (size_t)(m0 + row) * K + k0 + ss * 8,
            (char*)smA + (i * 256 + w * 64) * 16);
      gll16(Bt + (size_t)(n0 + row) * K + k0 + ss * 8,
            (char*)smB + (i * 256 + w * 64) * 16);
    }
    __syncthreads();
    #pragma unroll
    for (int kk = 0; kk < 2; ++kk) {
      bf16x8 a[4], b[4];
      #pragma unroll
      for (int m = 0; m < 4; ++m) {
        int row = wr * 64 + m * 16 + (l & 15);
        int off = (kk * 64 + ((l >> 4) << 4)) ^ ((row & 7) << 4);
        a[m] = *(const bf16x8*)((const char*)smA + row * 128 + off);
      }
      #pragma unroll
      for (int n = 0; n < 4; ++n) {
        int row = wc * 64 + n * 16 + (l & 15);
        int off = (kk * 64 + ((l >> 4) << 4)) ^ ((row & 7) << 4);
        b[n] = *(const bf16x8*)((const char*)smB + row * 128 + off);
      }
      #pragma unroll
      for (int m = 0; m < 4; ++m)
        #pragma unroll
        for (int n = 0; n < 4; ++n)
          acc[m][n] = __builtin_amdgcn_mfma_f32_16x16x32_bf16(a[m], b[n], acc[m][n], 0, 0, 0);
    }
  }

  #pragma unroll
  for (int m = 0; m < 4; ++m) {
    int row = m0 + wr * 64 + m * 16 + ((l >> 4) << 2);
    #pragma unroll
    for (int n = 0; n < 4; ++n) {
      int col = n0 + wc * 64 + n * 16 + (l & 15);
      float bv = BIAS ? bias[col] : 0.f;
      #pragma unroll
      for (int j = 0; j < 4; ++j) {
        float vv = acc[m][n][j] + bv;
        if (OUTF32) outf[(size_t)(row + j) * N + col] = vv;
        else        outb[(size_t)(row + j) * N + col] = f2b(vv);
      }
    }
  }
}

// ---------------- 256x256 8-phase counted-vmcnt bf16 GEMM (m201 template, exact) ----
// 512 thr = 8 waves (2M x 4N); wave (wm,wn) owns C rows wm*128..+127, cols wn*64..+63.
// BK=64, 4 phases/tile: phase p computes the wave's rows p*32..+31 x full K=64 (16 MFMA).
// B-frags read once per tile (p0, 8 x ds_read_b128, held in regs); A-frags 4 reads/phase.
// LDS 128 KiB = 2 bufs x {A0,A1,B0,B1} (each 128x64 bf16, 128B rows, slot XOR (row&7)).
// Stage order: T.p0 -> (T+1).A1 [other buf]; T.p1/p2/p3 -> (T+2).{B0,B1,A0} [current buf,
// B dead after p0]. Ledger: vmcnt(6) at T.p3 = 3 half-tiles in flight = (T+2).{B0,B1,A0};
// everything through (T+1).A1 landed => tile T+1 provably complete, stages 4-7 phases old.
// Tail (T >= nkt-2): skipped stages break the count -> full vmcnt(0) drain instead.
__global__ __launch_bounds__(512, 2) void gemm8ph(
    const short* __restrict__ A, const short* __restrict__ Bt,
    float* __restrict__ outf, int M, int N, int K, int nbx)
{
  __shared__ char sm[131072];
  const int t = threadIdx.x, l = t & 63, w = t >> 6;
  const int lq = l & 15, hi = l >> 4;
  const int wm = w >> 2, wn = w & 3;
  const int by = (int)blockIdx.x / nbx, bx = (int)blockIdx.x % nbx;
  const int m0 = by * 256, n0 = bx * 256;
  const int nkt = K >> 6;

  // region s: 0=B0 1=B1 2=A0 3=A1
  auto stage = [&](int tt, int s) {
    if (tt >= nkt) return;
    int kb = tt << 6;
    const short* base = (s < 2) ? Bt + (size_t)(n0 + (s << 7)) * K
                                : A  + (size_t)(m0 + ((s - 2) << 7)) * K;
    char* dst = sm + ((tt & 1) << 16) + (s < 2 ? 32768 + (s << 14) : ((s - 2) << 14));
    #pragma unroll
    for (int i = 0; i < 2; ++i) {
      int c = (i << 9) + t;
      int row = c >> 3, sl = c & 7;
      gll16(base + (size_t)row * K + kb + ((sl ^ (row & 7)) << 3), dst + c * 16);
    }
  };

  const f32x4 z = {0.f, 0.f, 0.f, 0.f};
  f32x4 acc[8][4];
  #pragma unroll
  for (int i = 0; i < 8; ++i)
    #pragma unroll
    for (int j = 0; j < 4; ++j) acc[i][j] = z;

  bf16x8 aC[2][2], bC[4][2];

  // prologue: T0 all 4 halves + T1.{B0,B1,A0}; drain so T0 fully landed (oldest 8 of 14)
  stage(0, 0); stage(0, 1); stage(0, 2); stage(0, 3);
  stage(1, 0); stage(1, 1); stage(1, 2);
  asm volatile("s_waitcnt vmcnt(6)" ::: "memory");
  __builtin_amdgcn_s_barrier();

#define PH(P, STT, STS, TAILV)                                              \
  {                                                                         \
    if ((P) == 0) {                                                         \
      _Pragma("unroll")                                                     \
      for (int fn = 0; fn < 4; ++fn) {                                      \
        int rb = (wn << 6) + (fn << 4) + lq;                                \
        const char* bb = sm + (bsel << 16) + 32768 + ((rb >> 7) << 14)      \
                         + (rb & 127) * 128;                                \
        _Pragma("unroll")                                                   \
        for (int kk = 0; kk < 2; ++kk)                                      \
          bC[fn][kk] = *(const bf16x8*)(bb + ((((kk << 2) + hi) ^ (rb & 7)) << 4)); \
      }                                                                     \
    }                                                                       \
    _Pragma("unroll")                                                       \
    for (int fr = 0; fr < 2; ++fr) {                                        \
      int lr = ((P) << 5) + (fr << 4) + lq;                                 \
      const char* ab = sm + (bsel << 16) + (wm << 14) + lr * 128;           \
      _Pragma("unroll")                                                     \
      for (int kk = 0; kk < 2; ++kk)                                        \
        aC[fr][kk] = *(const bf16x8*)(ab + ((((kk << 2) + hi) ^ (lr & 7)) << 4)); \
    }                                                                       \
    stage((STT), (STS));                                                    \
    __builtin_amdgcn_s_barrier();                                           \
    asm volatile("s_waitcnt lgkmcnt(0)" ::: "memory");                      \
    __builtin_amdgcn_s_setprio(1);                                          \
    _Pragma("unroll")                                                       \
    for (int kk = 0; kk < 2; ++kk)                                          \
      _Pragma("unroll")                                                     \
      for (int fr = 0; fr < 2; ++fr)                                        \
        _Pragma("unroll")                                                   \
        for (int fn = 0; fn < 4; ++fn)                                      \
          acc[(P) * 2 + fr][fn] = __builtin_amdgcn_mfma_f32_16x16x32_bf16(  \
              aC[fr][kk], bC[fn][kk], acc[(P) * 2 + fr][fn], 0, 0, 0);      \
    __builtin_amdgcn_s_setprio(0);                                          \
    if ((P) == 3) {                                                         \
      if (TAILV) asm volatile("s_waitcnt vmcnt(0)" ::: "memory");           \
      else       asm volatile("s_waitcnt vmcnt(6)" ::: "memory");           \
    }                                                                       \
    __builtin_amdgcn_s_barrier();                                           \
  }

  for (int T = 0; T < nkt; ++T) {
    const int bsel = T & 1;
    const bool tail = (T >= nkt - 2);
    PH(0, T + 1, 3, tail)   // stage (T+1).A1 -> other buf (dead since tile T-1)
    PH(1, T + 2, 0, tail)   // stage (T+2).B0 -> current buf (B0 dead after p0)
    PH(2, T + 2, 1, tail)   // stage (T+2).B1 -> current buf (dead)
    PH(3, T + 2, 2, tail)   // stage (T+2).A0; vmcnt closes ledger for tile T+1
  }
#undef PH

  // epilogue: row = m0 + wm*128 + fm*16 + hi*4 + j, col = n0 + wn*64 + fn*16 + lq
  #pragma unroll
  for (int fm = 0; fm < 8; ++fm) {
    int r0 = m0 + (wm << 7) + (fm << 4) + (hi << 2);
    #pragma unroll
    for (int fn = 0; fn < 4; ++fn) {
      int cc = n0 + (wn << 6) + (fn << 4) + lq;
      #pragma unroll
      for (int j = 0; j < 4; ++j)
        outf[(size_t)(r0 + j) * N + cc] = acc[fm][fn][j];
    }
  }
}

// ---------------- RoPE + split, vectorized (8 bf16/thread) ----------------
// q is pre-scaled by QSCALE (softmax runs in exp2 domain).
__global__ void rope_split(const short* __restrict__ mixed, const float* __restrict__ rope,
                           short* __restrict__ qo, short* __restrict__ ko, short* __restrict__ vo)
{
  const int CH = QKVN / 8;                 // 576 chunks per row
  int idx = blockIdx.x * blockDim.x + threadIdx.x;
  if (idx >= B_ * SQ * CH) return;
  int row = idx / CH;
  int cc = (idx - row * CH) * 8;
  int b = row >> 11, s = row & 2047;

  bf16x8 xv = *(const bf16x8*)(mixed + (size_t)row * QKVN + cc);
  float x[8];
  #pragma unroll
  for (int i = 0; i < 8; ++i) x[i] = b2f(xv[i]);

  int sect, hh, d = cc & 127;
  if (cc < 4096)      { sect = 0; hh = cc >> 7; }
  else if (cc < 4352) { sect = 1; hh = (cc - 4096) >> 7; }
  else                { sect = 2; hh = (cc - 4352) >> 7; }

  if (sect < 2 && d < 64) {                // rot_dim=64, interleaved pairs
    float4 ca = *(const float4*)(rope + s * 64 + d);
    float4 cb = *(const float4*)(rope + s * 64 + d + 4);
    float t0;
    t0 = x[0]*ca.x - x[1]*ca.y; x[1] = x[1]*ca.x + x[0]*ca.y; x[0] = t0;
    t0 = x[2]*ca.z - x[3]*ca.w; x[3] = x[3]*ca.z + x[2]*ca.w; x[2] = t0;
    t0 = x[4]*cb.x - x[5]*cb.y; x[5] = x[5]*cb.x + x[4]*cb.y; x[4] = t0;
    t0 = x[6]*cb.z - x[7]*cb.w; x[7] = x[7]*cb.z + x[6]*cb.w; x[6] = t0;
  }
  if (sect == 0) {
    #pragma unroll
    for (int i = 0; i < 8; ++i) x[i] *= QSCALE;
  }

  short* dst; size_t oidx;
  if (sect == 0)      { dst = qo; oidx = (((size_t)(b * NHEAD + hh) * SQ) + s) * HDIM + d; }
  else if (sect == 1) { dst = ko; oidx = (((size_t)(b * NGRP + hh) * SQ) + s) * HDIM + d; }
  else                { dst = vo; oidx = (((size_t)(b * NGRP + hh) * SQ) + s) * HDIM + d; }
  bf16x8 ov;
  #pragma unroll
  for (int i = 0; i < 8; ++i) ov[i] = f2b(x[i]);
  *(bf16x8*)(dst + oidx) = ov;
}

// ---------------- causal GQA flash attention (r5 proven structure + T5 setprio) ----
__global__ __launch_bounds__(512, 2) void attn_fwd(
    const short* __restrict__ q, const short* __restrict__ k,
    const short* __restrict__ v, short* __restrict__ ctx)
{
  __shared__ short smem[8192 + 9216];      // smK 64x128 (linear, swizzled), smV 128x72 (V^T)
  short* smK = smem;
  short* smV = smem + 8192;

  const int h = blockIdx.y, b = blockIdx.z;
  const int g = h >> 4;                    // GQA group
  const int t = threadIdx.x, l = t & 63, w = t >> 6;
  const int lq = l & 15, hi = l >> 4;

  const short* qbase = q + ((size_t)(b * NHEAD + h) * SQ) * HDIM;
  const short* kbase = k + ((size_t)(b * NGRP + g) * SQ) * HDIM;
  const short* vbase = v + ((size_t)(b * NGRP + g) * SQ) * HDIM;

  const f32x4 z = {0.f, 0.f, 0.f, 0.f};

  for (int pass = 0; pass < 2; ++pass) {
    const int s = pass ? (7 - (int)blockIdx.x) : (int)blockIdx.x;
    const int q0 = s * 256;
    const int qw = q0 + w * 32;
    const int nkt = 4 * s + 4;             // 64-key tiles for this pass

    bf16x8 qf[2][4];
    #pragma unroll
    for (int fq = 0; fq < 2; ++fq)
      #pragma unroll
      for (int kf = 0; kf < 4; ++kf)
        qf[fq][kf] = *(const bf16x8*)(qbase + (size_t)(qw + fq * 16 + lq) * HDIM + kf * 32 + hi * 8);

    f32x4 of[2][8];
    #pragma unroll
    for (int a = 0; a < 2; ++a)
      #pragma unroll
      for (int d = 0; d < 8; ++d) of[a][d] = z;
    float mrow[2] = {-1e30f, -1e30f};
    float lrow[2] = {0.f, 0.f};

    for (int kt = 0; kt < nkt; ++kt) {
      const int kb = kt * 64;
      __syncthreads();
      #pragma unroll
      for (int i = 0; i < 2; ++i) {
        int c = t + i * 512;
        int row = c >> 4, slot = c & 15;
        int ss = slot ^ (row & 7);
        gll16(kbase + (size_t)(kb + row) * HDIM + ss * 8,
              (char*)smK + (i * 512 + w * 64) * 16);
      }
      #pragma unroll
      for (int i = 0; i < 2; ++i) {
        int c = t + i * 512;
        int key = c & 63, d0 = (c >> 6) << 3;
        bf16x8 vv = *(const bf16x8*)(vbase + (size_t)(kb + key) * HDIM + d0);
        #pragma unroll
        for (int jj = 0; jj < 8; ++jj)
          smV[(d0 + jj) * 72 + key] = vv[jj];
      }
      __syncthreads();

      if (kb > qw + 31) continue;          // causal skip (barriers already done)

      f32x4 st[2][4];
      #pragma unroll
      for (int fq = 0; fq < 2; ++fq)
        #pragma unroll
        for (int fk = 0; fk < 4; ++fk) st[fq][fk] = z;
      __builtin_amdgcn_s_setprio(1);
      #pragma unroll
      for (int kf = 0; kf < 4; ++kf) {
        bf16x8 kfr[4];
        #pragma unroll
        for (int fk = 0; fk < 4; ++fk) {
          int row = fk * 16 + lq;
          int slot = (kf * 4 + hi) ^ (row & 7);
          kfr[fk] = *(const bf16x8*)((const char*)smK + row * 256 + slot * 16);
        }
        #pragma unroll
        for (int fq = 0; fq < 2; ++fq)
          #pragma unroll
          for (int fk = 0; fk < 4; ++fk)
            st[fq][fk] = __builtin_amdgcn_mfma_f32_16x16x32_bf16(kfr[fk], qf[fq][kf], st[fq][fk], 0, 0, 0);
      }
      __builtin_amdgcn_s_setprio(0);

      bf16x4 pa[2][4];
      #pragma unroll
      for (int fq = 0; fq < 2; ++fq) {
        float sv[16];
        #pragma unroll
        for (int fk = 0; fk < 4; ++fk)
          #pragma unroll
          for (int j = 0; j < 4; ++j) sv[fk * 4 + j] = st[fq][fk][j];
        if (kb + 63 > qw + fq * 16) {
          int qrow = qw + fq * 16 + lq;
          #pragma unroll
          for (int fk = 0; fk < 4; ++fk)
            #pragma unroll
            for (int j = 0; j < 4; ++j)
              if (kb + fk * 16 + hi * 4 + j > qrow) sv[fk * 4 + j] = -1e30f;
        }
        float mx = sv[0];
        #pragma unroll
        for (int i = 1; i < 16; ++i) mx = fmaxf(mx, sv[i]);
        mx = fmaxf(mx, __shfl_xor(mx, 16));
        mx = fmaxf(mx, __shfl_xor(mx, 32));
        if (__any(mx > mrow[fq] + 11.0f)) {
          float mn = fmaxf(mrow[fq], mx);
          float corr = exp2f(mrow[fq] - mn);
          mrow[fq] = mn;
          lrow[fq] *= corr;
          float cj[4];
          #pragma unroll
          for (int j = 0; j < 4; ++j) cj[j] = __shfl(corr, hi * 4 + j);
          #pragma unroll
          for (int df = 0; df < 8; ++df)
            #pragma unroll
            for (int j = 0; j < 4; ++j) of[fq][df][j] *= cj[j];
        }
        float rs = 0.f;
        #pragma unroll
        for (int i = 0; i < 16; ++i) { sv[i] = exp2f(sv[i] - mrow[fq]); rs += sv[i]; }
        rs += __shfl_xor(rs, 16);
        rs += __shfl_xor(rs, 32);
        lrow[fq] += rs;
        #pragma unroll
        for (int fk = 0; fk < 4; ++fk) {
          bf16x4 p;
          p[0] = f2b(sv[fk * 4 + 0]); p[1] = f2b(sv[fk * 4 + 1]);
          p[2] = f2b(sv[fk * 4 + 2]); p[3] = f2b(sv[fk * 4 + 3]);
          pa[fq][fk] = p;
        }
      }

      __builtin_amdgcn_s_setprio(1);
      #pragma unroll
      for (int fk = 0; fk < 4; ++fk) {
        bf16x4 vb[8];
        #pragma unroll
        for (int df = 0; df < 8; ++df)
          vb[df] = *(const bf16x4*)(smV + (df * 16 + lq) * 72 + fk * 16 + hi * 4);
        #pragma unroll
        for (int df = 0; df < 8; ++df) {
          of[0][df] = __builtin_amdgcn_mfma_f32_16x16x16bf16_1k(pa[0][fk], vb[df], of[0][df], 0, 0, 0);
          of[1][df] = __builtin_amdgcn_mfma_f32_16x16x16bf16_1k(pa[1][fk], vb[df], of[1][df], 0, 0, 0);
        }
      }
      __builtin_amdgcn_s_setprio(0);
    }

    #pragma unroll
    for (int fq = 0; fq < 2; ++fq) {
      float inv = 1.f / lrow[fq];
      float ij[4];
      #pragma unroll
      for (int j = 0; j < 4; ++j) ij[j] = __shfl(inv, hi * 4 + j);
      #pragma unroll
      for (int j = 0; j < 4; ++j) {
        int srow = qw + fq * 16 + hi * 4 + j;
        size_t rbase = ((size_t)(b * SQ + srow)) * (NHEAD * HDIM) + (size_t)h * HDIM;
        #pragma unroll
        for (int df = 0; df < 8; ++df)
          ctx[rbase + df * 16 + lq] = f2b(of[fq][df][j] * ij[j]);
      }
    }
    __syncthreads();   // protect LDS before next pass re-stages
  }
}

extern "C" void kernel_launch(void* const* d_in, const int* in_sizes, int n_in,
                              void* d_out, int out_size, void* d_ws, size_t ws_size,
                              hipStream_t stream)
{
  const float* hidden = (const float*)d_in[0];
  const float* rope   = (const float*)d_in[1];
  const float* Wqkv   = (const float*)d_in[2];
  const float* bqkv   = (const float*)d_in[3];
  const float* Wd     = (const float*)d_in[4];
  float* out = (float*)d_out;

  // workspace layout (bytes), with aliasing:
  //   [0]          hs_bf16 (33.5MB)  -> later q_r (same size)
  //   [33554432]   Wqkv_t  (37.7MB)  -> later Wdense_t
  //   [71303168]   mixed   (37.7MB)  -> later ctx
  //   [109051904]  k_r (2MB)
  //   [111149056]  v_r (2MB)         total 113246208 B
  if (ws_size < 113246208ULL) return;
  char* ws = (char*)d_ws;
  short* hsb   = (short*)(ws);
  short* wT    = (short*)(ws + 33554432);
  short* mixed = (short*)(ws + 71303168);
  short* k_r   = (short*)(ws + 109051904);
  short* v_r   = (short*)(ws + 111149056);

  conv_f32_bf16<<<16384, 256, 0, stream>>>(hidden, hsb, B_ * SQ * H_);
  transpose_f32_bf16<<<dim3(QKVN / 64, H_ / 64), 256, 0, stream>>>(Wqkv, wT, H_, QKVN);
  gemm_bf16<true, false><<<dim3(QKVN / 128, (B_ * SQ) / 128), 256, 0, stream>>>(
      hsb, wT, bqkv, mixed, nullptr, B_ * SQ, QKVN, H_);
  rope_split<<<9216, 256, 0, stream>>>(mixed, rope, hsb, k_r, v_r);
  transpose_f32_bf16<<<dim3(H_ / 64, H_ / 64), 256, 0, stream>>>(Wd, wT, H_, H_);
  attn_fwd<<<dim3(4, NHEAD, B_), 512, 0, stream>>>(hsb, k_r, v_r, mixed);
  // dense: 256x256 8-phase template GEMM; grid 16x16 = 256 blocks = 1/CU
  gemm8ph<<<256, 512, 0, stream>>>(mixed, wT, out, B_ * SQ, H_, H_, H_ / 256);
}

// Round 13
// 529.279 us; speedup vs baseline: 1.0438x; 1.0438x over previous
//
#include <hip/hip_runtime.h>
#include <hip/hip_bf16.h>
#include <stdint.h>

// Problem constants
#define B_    2
#define SQ    2048
#define H_    4096
#define NHEAD 32
#define HDIM  128
#define NGRP  2
#define QKVN  4608          // NH*HD + 2*NG*HD
#define SCALE 0.08838834764831845f   // 1/sqrt(128), coeff=1
#define QSCALE (0.08838834764831845f * 1.4426950408889634f)  // SCALE*log2(e), exp2 softmax

typedef __attribute__((ext_vector_type(8))) short bf16x8;
typedef __attribute__((ext_vector_type(4))) short bf16x4;
typedef __attribute__((ext_vector_type(4))) float f32x4;

__device__ __forceinline__ float b2f(short s) {
  union { float f; unsigned u; } x; x.u = ((unsigned)(unsigned short)s) << 16; return x.f;
}
__device__ __forceinline__ short f2b(float f) {
  union { float f; unsigned u; } x; x.f = f;
  unsigned r = x.u + 0x7fffu + ((x.u >> 16) & 1u);  // RNE
  return (short)(r >> 16);
}
__device__ __forceinline__ void gll16(const void* g, void* l) {
  __builtin_amdgcn_global_load_lds(
      (const __attribute__((address_space(1))) unsigned int*)g,
      (__attribute__((address_space(3))) unsigned int*)l, 16, 0, 0);
}

// ---------------- f32 -> bf16 convert (vectorized) ----------------
__global__ void conv_f32_bf16(const float* __restrict__ x, short* __restrict__ y, int n) {
  int i = (blockIdx.x * blockDim.x + threadIdx.x) * 4;
  if (i >= n) return;
  float4 v = *(const float4*)(x + i);
  union { short s[4]; uint2 u; } o;
  o.s[0] = f2b(v.x); o.s[1] = f2b(v.y); o.s[2] = f2b(v.z); o.s[3] = f2b(v.w);
  *(uint2*)(y + i) = o.u;
}

// ---------------- transpose f32 (RxC) -> bf16 (CxR), 64x64 tile, float4 loads ------
__global__ void transpose_f32_bf16(const float* __restrict__ W, short* __restrict__ Wt,
                                   int R, int C) {
  __shared__ float tile[64][65];
  int c0 = blockIdx.x * 64, r0 = blockIdx.y * 64;
  int tx = threadIdx.x & 15, ty = threadIdx.x >> 4;
  #pragma unroll
  for (int i = 0; i < 4; ++i) {
    float4 v = *(const float4*)(W + (size_t)(r0 + ty + 16 * i) * C + c0 + tx * 4);
    tile[ty + 16 * i][tx * 4 + 0] = v.x;
    tile[ty + 16 * i][tx * 4 + 1] = v.y;
    tile[ty + 16 * i][tx * 4 + 2] = v.z;
    tile[ty + 16 * i][tx * 4 + 3] = v.w;
  }
  __syncthreads();
  #pragma unroll
  for (int i = 0; i < 4; ++i) {
    int orow = ty + 16 * i;
    bf16x4 o;
    #pragma unroll
    for (int j = 0; j < 4; ++j) o[j] = f2b(tile[tx * 4 + j][orow]);
    *(bf16x4*)(Wt + (size_t)(c0 + orow) * R + r0 + tx * 4) = o;
  }
}

// ---------------- 128x128 bf16 MFMA GEMM (proven m97 structure, 2D grid) ----------------
template<bool BIAS, bool OUTF32>
__global__ __launch_bounds__(256, 2) void gemm_bf16(
    const short* __restrict__ A, const short* __restrict__ Bt,
    const float* __restrict__ bias, short* __restrict__ outb,
    float* __restrict__ outf, int M, int N, int K)
{
  __shared__ short smA[128 * 64];
  __shared__ short smB[128 * 64];
  const int t = threadIdx.x;
  const int l = t & 63;
  const int w = t >> 6;
  const int wr = w >> 1, wc = w & 1;
  const int m0 = blockIdx.y * 128, n0 = blockIdx.x * 128;

  const f32x4 z = {0.f, 0.f, 0.f, 0.f};
  f32x4 acc[4][4];
  #pragma unroll
  for (int m = 0; m < 4; ++m)
    #pragma unroll
    for (int n = 0; n < 4; ++n) acc[m][n] = z;

  for (int k0 = 0; k0 < K; k0 += 64) {
    __syncthreads();
    #pragma unroll
    for (int i = 0; i < 4; ++i) {
      int c = t + i * 256;
      int row = c >> 3, slot = c & 7;
      int ss = slot ^ (row & 7);
      gll16(A  + (size_t)(m0 + row) * K + k0 + ss * 8,
            (char*)smA + (i * 256 + w * 64) * 16);
      gll16(Bt + (size_t)(n0 + row) * K + k0 + ss * 8,
            (char*)smB + (i * 256 + w * 64) * 16);
    }
    __syncthreads();
    #pragma unroll
    for (int kk = 0; kk < 2; ++kk) {
      bf16x8 a[4], b[4];
      #pragma unroll
      for (int m = 0; m < 4; ++m) {
        int row = wr * 64 + m * 16 + (l & 15);
        int off = (kk * 64 + ((l >> 4) << 4)) ^ ((row & 7) << 4);
        a[m] = *(const bf16x8*)((const char*)smA + row * 128 + off);
      }
      #pragma unroll
      for (int n = 0; n < 4; ++n) {
        int row = wc * 64 + n * 16 + (l & 15);
        int off = (kk * 64 + ((l >> 4) << 4)) ^ ((row & 7) << 4);
        b[n] = *(const bf16x8*)((const char*)smB + row * 128 + off);
      }
      #pragma unroll
      for (int m = 0; m < 4; ++m)
        #pragma unroll
        for (int n = 0; n < 4; ++n)
          acc[m][n] = __builtin_amdgcn_mfma_f32_16x16x32_bf16(a[m], b[n], acc[m][n], 0, 0, 0);
    }
  }

  #pragma unroll
  for (int m = 0; m < 4; ++m) {
    int row = m0 + wr * 64 + m * 16 + ((l >> 4) << 2);
    #pragma unroll
    for (int n = 0; n < 4; ++n) {
      int col = n0 + wc * 64 + n * 16 + (l & 15);
      float bv = BIAS ? bias[col] : 0.f;
      #pragma unroll
      for (int j = 0; j < 4; ++j) {
        float vv = acc[m][n][j] + bv;
        if (OUTF32) outf[(size_t)(row + j) * N + col] = vv;
        else        outb[(size_t)(row + j) * N + col] = f2b(vv);
      }
    }
  }
}

// ---------------- RoPE + split, vectorized (8 bf16/thread) ----------------
// q is pre-scaled by QSCALE (softmax runs in exp2 domain).
__global__ void rope_split(const short* __restrict__ mixed, const float* __restrict__ rope,
                           short* __restrict__ qo, short* __restrict__ ko, short* __restrict__ vo)
{
  const int CH = QKVN / 8;                 // 576 chunks per row
  int idx = blockIdx.x * blockDim.x + threadIdx.x;
  if (idx >= B_ * SQ * CH) return;
  int row = idx / CH;
  int cc = (idx - row * CH) * 8;
  int b = row >> 11, s = row & 2047;

  bf16x8 xv = *(const bf16x8*)(mixed + (size_t)row * QKVN + cc);
  float x[8];
  #pragma unroll
  for (int i = 0; i < 8; ++i) x[i] = b2f(xv[i]);

  int sect, hh, d = cc & 127;
  if (cc < 4096)      { sect = 0; hh = cc >> 7; }
  else if (cc < 4352) { sect = 1; hh = (cc - 4096) >> 7; }
  else                { sect = 2; hh = (cc - 4352) >> 7; }

  if (sect < 2 && d < 64) {                // rot_dim=64, interleaved pairs
    float4 ca = *(const float4*)(rope + s * 64 + d);
    float4 cb = *(const float4*)(rope + s * 64 + d + 4);
    float t0;
    t0 = x[0]*ca.x - x[1]*ca.y; x[1] = x[1]*ca.x + x[0]*ca.y; x[0] = t0;
    t0 = x[2]*ca.z - x[3]*ca.w; x[3] = x[3]*ca.z + x[2]*ca.w; x[2] = t0;
    t0 = x[4]*cb.x - x[5]*cb.y; x[5] = x[5]*cb.x + x[4]*cb.y; x[4] = t0;
    t0 = x[6]*cb.z - x[7]*cb.w; x[7] = x[7]*cb.z + x[6]*cb.w; x[6] = t0;
  }
  if (sect == 0) {
    #pragma unroll
    for (int i = 0; i < 8; ++i) x[i] *= QSCALE;
  }

  short* dst; size_t oidx;
  if (sect == 0)      { dst = qo; oidx = (((size_t)(b * NHEAD + hh) * SQ) + s) * HDIM + d; }
  else if (sect == 1) { dst = ko; oidx = (((size_t)(b * NGRP + hh) * SQ) + s) * HDIM + d; }
  else                { dst = vo; oidx = (((size_t)(b * NGRP + hh) * SQ) + s) * HDIM + d; }
  bf16x8 ov;
  #pragma unroll
  for (int i = 0; i < 8; ++i) ov[i] = f2b(x[i]);
  *(bf16x8*)(dst + oidx) = ov;
}

// ---------------- causal GQA flash attention, double-buffered pipelined staging ----
// grid (4, NH, B), 512 threads = 8 waves; block bx does super-tiles {bx, 7-bx} in two
// passes -> uniform 36 key-tiles/block. Per tile t: issue gll16 K(t+1) + global V(t+1)
// -> regs BEFORE compute (HBM latency hides under QK/softmax/PV), write V-regs -> LDS
// after compute (compiler's vmcnt covers), ONE barrier per tile. K/V double-buffered
// (LDS 69.6 KB). LDS buffer pointers computed per-iteration via offsets (hipcc can't
// static-init pointer arrays with addrspace(3) casts). Swapped QK^T in-register
// softmax (exp2 domain, Q pre-scaled), defer-max rescale, PV via 16x16x16, T5 setprio.
__global__ __launch_bounds__(512, 2) void attn_fwd(
    const short* __restrict__ q, const short* __restrict__ k,
    const short* __restrict__ v, short* __restrict__ ctx)
{
  __shared__ short smem[2 * (8192 + 9216)];

  const int h = blockIdx.y, b = blockIdx.z;
  const int g = h >> 4;                    // GQA group
  const int t = threadIdx.x, l = t & 63, w = t >> 6;
  const int lq = l & 15, hi = l >> 4;

  const short* qbase = q + ((size_t)(b * NHEAD + h) * SQ) * HDIM;
  const short* kbase = k + ((size_t)(b * NGRP + g) * SQ) * HDIM;
  const short* vbase = v + ((size_t)(b * NGRP + g) * SQ) * HDIM;

  // per-thread staging coordinates (constant across tiles)
  const int kc0 = t, kc1 = t + 512;              // K chunks
  const int krow0 = kc0 >> 4, kss0 = (kc0 & 15) ^ (krow0 & 7);
  const int krow1 = kc1 >> 4, kss1 = (kc1 & 15) ^ (krow1 & 7);
  const int vkey0 = kc0 & 63, vd0 = (kc0 >> 6) << 3;
  const int vkey1 = kc1 & 63, vd1 = (kc1 >> 6) << 3;

  const f32x4 z = {0.f, 0.f, 0.f, 0.f};

  for (int pass = 0; pass < 2; ++pass) {
    const int s = pass ? (7 - (int)blockIdx.x) : (int)blockIdx.x;
    const int q0 = s * 256;
    const int qw = q0 + w * 32;
    const int nkt = 4 * s + 4;             // 64-key tiles for this pass

    bf16x8 qf[2][4];
    #pragma unroll
    for (int fq = 0; fq < 2; ++fq)
      #pragma unroll
      for (int kf = 0; kf < 4; ++kf)
        qf[fq][kf] = *(const bf16x8*)(qbase + (size_t)(qw + fq * 16 + lq) * HDIM + kf * 32 + hi * 8);

    f32x4 of[2][8];
    #pragma unroll
    for (int a = 0; a < 2; ++a)
      #pragma unroll
      for (int d = 0; d < 8; ++d) of[a][d] = z;
    float mrow[2] = {-1e30f, -1e30f};
    float lrow[2] = {0.f, 0.f};

    // prologue: stage tile 0 into buffer 0
    {
      short* K0 = smem;
      short* V0 = smem + 16384;
      gll16(kbase + (size_t)krow0 * HDIM + kss0 * 8, (char*)K0 + kc0 * 16);
      gll16(kbase + (size_t)krow1 * HDIM + kss1 * 8, (char*)K0 + kc1 * 16);
      bf16x8 vv0 = *(const bf16x8*)(vbase + (size_t)vkey0 * HDIM + vd0);
      bf16x8 vv1 = *(const bf16x8*)(vbase + (size_t)vkey1 * HDIM + vd1);
      #pragma unroll
      for (int jj = 0; jj < 8; ++jj) V0[(vd0 + jj) * 72 + vkey0] = vv0[jj];
      #pragma unroll
      for (int jj = 0; jj < 8; ++jj) V0[(vd1 + jj) * 72 + vkey1] = vv1[jj];
    }
    __syncthreads();

    for (int kt = 0; kt < nkt; ++kt) {
      const int kb = kt * 64;
      const int cur = kt & 1;
      const short* Kc = smem + cur * 8192;
      const short* Vc = smem + 16384 + cur * 9216;
      short* Kn = smem + (cur ^ 1) * 8192;
      short* Vn = smem + 16384 + (cur ^ 1) * 9216;
      const bool have_next = (kt + 1 < nkt);

      bf16x8 vv0, vv1;
      if (have_next) {
        const int kbn = kb + 64;
        gll16(kbase + (size_t)(kbn + krow0) * HDIM + kss0 * 8, (char*)Kn + kc0 * 16);
        gll16(kbase + (size_t)(kbn + krow1) * HDIM + kss1 * 8, (char*)Kn + kc1 * 16);
        vv0 = *(const bf16x8*)(vbase + (size_t)(kbn + vkey0) * HDIM + vd0);
        vv1 = *(const bf16x8*)(vbase + (size_t)(kbn + vkey1) * HDIM + vd1);
        __builtin_amdgcn_sched_barrier(0);   // pin load-issue before compute
      }

      if (kb <= qw + 31) {                   // causal-relevant for this wave
        f32x4 st[2][4];
        #pragma unroll
        for (int fq = 0; fq < 2; ++fq)
          #pragma unroll
          for (int fk = 0; fk < 4; ++fk) st[fq][fk] = z;
        __builtin_amdgcn_s_setprio(1);
        #pragma unroll
        for (int kf = 0; kf < 4; ++kf) {
          bf16x8 kfr[4];
          #pragma unroll
          for (int fk = 0; fk < 4; ++fk) {
            int row = fk * 16 + lq;
            int slot = (kf * 4 + hi) ^ (row & 7);
            kfr[fk] = *(const bf16x8*)((const char*)Kc + row * 256 + slot * 16);
          }
          #pragma unroll
          for (int fq = 0; fq < 2; ++fq)
            #pragma unroll
            for (int fk = 0; fk < 4; ++fk)
              st[fq][fk] = __builtin_amdgcn_mfma_f32_16x16x32_bf16(kfr[fk], qf[fq][kf], st[fq][fk], 0, 0, 0);
        }
        __builtin_amdgcn_s_setprio(0);

        bf16x4 pa[2][4];
        #pragma unroll
        for (int fq = 0; fq < 2; ++fq) {
          float sv[16];
          #pragma unroll
          for (int fk = 0; fk < 4; ++fk)
            #pragma unroll
            for (int j = 0; j < 4; ++j) sv[fk * 4 + j] = st[fq][fk][j];
          if (kb + 63 > qw + fq * 16) {      // diagonal tile: causal mask
            int qrow = qw + fq * 16 + lq;
            #pragma unroll
            for (int fk = 0; fk < 4; ++fk)
              #pragma unroll
              for (int j = 0; j < 4; ++j)
                if (kb + fk * 16 + hi * 4 + j > qrow) sv[fk * 4 + j] = -1e30f;
          }
          float mx = sv[0];
          #pragma unroll
          for (int i = 1; i < 16; ++i) mx = fmaxf(mx, sv[i]);
          mx = fmaxf(mx, __shfl_xor(mx, 16));
          mx = fmaxf(mx, __shfl_xor(mx, 32));
          if (__any(mx > mrow[fq] + 11.0f)) {
            float mn = fmaxf(mrow[fq], mx);
            float corr = exp2f(mrow[fq] - mn);
            mrow[fq] = mn;
            lrow[fq] *= corr;
            float cj[4];
            #pragma unroll
            for (int j = 0; j < 4; ++j) cj[j] = __shfl(corr, hi * 4 + j);
            #pragma unroll
            for (int df = 0; df < 8; ++df)
              #pragma unroll
              for (int j = 0; j < 4; ++j) of[fq][df][j] *= cj[j];
          }
          float rs = 0.f;
          #pragma unroll
          for (int i = 0; i < 16; ++i) { sv[i] = exp2f(sv[i] - mrow[fq]); rs += sv[i]; }
          rs += __shfl_xor(rs, 16);
          rs += __shfl_xor(rs, 32);
          lrow[fq] += rs;
          #pragma unroll
          for (int fk = 0; fk < 4; ++fk) {
            bf16x4 p;
            p[0] = f2b(sv[fk * 4 + 0]); p[1] = f2b(sv[fk * 4 + 1]);
            p[2] = f2b(sv[fk * 4 + 2]); p[3] = f2b(sv[fk * 4 + 3]);
            pa[fq][fk] = p;
          }
        }

        __builtin_amdgcn_s_setprio(1);
        #pragma unroll
        for (int fk = 0; fk < 4; ++fk) {
          bf16x4 vb[8];
          #pragma unroll
          for (int df = 0; df < 8; ++df)
            vb[df] = *(const bf16x4*)(Vc + (df * 16 + lq) * 72 + fk * 16 + hi * 4);
          #pragma unroll
          for (int df = 0; df < 8; ++df) {
            of[0][df] = __builtin_amdgcn_mfma_f32_16x16x16bf16_1k(pa[0][fk], vb[df], of[0][df], 0, 0, 0);
            of[1][df] = __builtin_amdgcn_mfma_f32_16x16x16bf16_1k(pa[1][fk], vb[df], of[1][df], 0, 0, 0);
          }
        }
        __builtin_amdgcn_s_setprio(0);
      }

      if (have_next) {                      // write V(t+1) regs -> LDS (vmcnt implicit)
        #pragma unroll
        for (int jj = 0; jj < 8; ++jj) Vn[(vd0 + jj) * 72 + vkey0] = vv0[jj];
        #pragma unroll
        for (int jj = 0; jj < 8; ++jj) Vn[(vd1 + jj) * 72 + vkey1] = vv1[jj];
      }
      __syncthreads();                      // K(t+1) (gll16) + V(t+1) ready
    }

    // epilogue: O rows q = qw+fq*16+hi*4+j, cols d = df*16+lq
    #pragma unroll
    for (int fq = 0; fq < 2; ++fq) {
      float inv = 1.f / lrow[fq];
      float ij[4];
      #pragma unroll
      for (int j = 0; j < 4; ++j) ij[j] = __shfl(inv, hi * 4 + j);
      #pragma unroll
      for (int j = 0; j < 4; ++j) {
        int srow = qw + fq * 16 + hi * 4 + j;
        size_t rbase = ((size_t)(b * SQ + srow)) * (NHEAD * HDIM) + (size_t)h * HDIM;
        #pragma unroll
        for (int df = 0; df < 8; ++df)
          ctx[rbase + df * 16 + lq] = f2b(of[fq][df][j] * ij[j]);
      }
    }
    __syncthreads();   // protect LDS before next pass re-stages
  }
}

extern "C" void kernel_launch(void* const* d_in, const int* in_sizes, int n_in,
                              void* d_out, int out_size, void* d_ws, size_t ws_size,
                              hipStream_t stream)
{
  const float* hidden = (const float*)d_in[0];
  const float* rope   = (const float*)d_in[1];
  const float* Wqkv   = (const float*)d_in[2];
  const float* bqkv   = (const float*)d_in[3];
  const float* Wd     = (const float*)d_in[4];
  float* out = (float*)d_out;

  // workspace layout (bytes), with aliasing:
  //   [0]          hs_bf16 (33.5MB)  -> later q_r (same size)
  //   [33554432]   Wqkv_t  (37.7MB)  -> later Wdense_t
  //   [71303168]   mixed   (37.7MB)  -> later ctx
  //   [109051904]  k_r (2MB)
  //   [111149056]  v_r (2MB)         total 113246208 B
  if (ws_size < 113246208ULL) return;
  char* ws = (char*)d_ws;
  short* hsb   = (short*)(ws);
  short* wT    = (short*)(ws + 33554432);
  short* mixed = (short*)(ws + 71303168);
  short* k_r   = (short*)(ws + 109051904);
  short* v_r   = (short*)(ws + 111149056);

  conv_f32_bf16<<<16384, 256, 0, stream>>>(hidden, hsb, B_ * SQ * H_);
  transpose_f32_bf16<<<dim3(QKVN / 64, H_ / 64), 256, 0, stream>>>(Wqkv, wT, H_, QKVN);
  gemm_bf16<true, false><<<dim3(QKVN / 128, (B_ * SQ) / 128), 256, 0, stream>>>(
      hsb, wT, bqkv, mixed, nullptr, B_ * SQ, QKVN, H_);
  rope_split<<<9216, 256, 0, stream>>>(mixed, rope, hsb, k_r, v_r);
  transpose_f32_bf16<<<dim3(H_ / 64, H_ / 64), 256, 0, stream>>>(Wd, wT, H_, H_);
  attn_fwd<<<dim3(4, NHEAD, B_), 512, 0, stream>>>(hsb, k_r, v_r, mixed);
  gemm_bf16<false, true><<<dim3(H_ / 128, (B_ * SQ) / 128), 256, 0, stream>>>(
      mixed, wT, nullptr, nullptr, out, B_ * SQ, H_, H_);
}